// Round 15
// baseline (2991.025 us; speedup 1.0000x reference)
//
#include <hip/hip_runtime.h>

#define R     8192
#define C1    8213
#define C2    8192
#define KROW  8224      // K/GM row stride in BYTES (514 x 16B chunks, zero-padded)
#define TROW  8192      // KT row stride in BYTES (512 x 16B chunks)
#define NKC   514
#define NTC   512
#define CPF   8224      // v length in floats
#define BLKJ  1024      // outputs per build block

typedef float f32x2 __attribute__((ext_vector_type(2)));

__device__ __forceinline__ void fp8x16_to_f(const int4 w, float f[16]) {
    f32x2 p;
    p = __builtin_amdgcn_cvt_pk_f32_fp8(w.x, false); f[0]  = p.x; f[1]  = p.y;
    p = __builtin_amdgcn_cvt_pk_f32_fp8(w.x, true);  f[2]  = p.x; f[3]  = p.y;
    p = __builtin_amdgcn_cvt_pk_f32_fp8(w.y, false); f[4]  = p.x; f[5]  = p.y;
    p = __builtin_amdgcn_cvt_pk_f32_fp8(w.y, true);  f[6]  = p.x; f[7]  = p.y;
    p = __builtin_amdgcn_cvt_pk_f32_fp8(w.z, false); f[8]  = p.x; f[9]  = p.y;
    p = __builtin_amdgcn_cvt_pk_f32_fp8(w.z, true);  f[10] = p.x; f[11] = p.y;
    p = __builtin_amdgcn_cvt_pk_f32_fp8(w.w, false); f[12] = p.x; f[13] = p.y;
    p = __builtin_amdgcn_cvt_pk_f32_fp8(w.w, true);  f[14] = p.x; f[15] = p.y;
}

__device__ __forceinline__ float fp8_to_f(int byte) {
    f32x2 p = __builtin_amdgcn_cvt_pk_f32_fp8(byte & 0xff, false);
    return p.x;
}

__device__ __forceinline__ float gm_label(float sc, int lab) {
    if (lab == 0) return fmaxf(-0.02f - sc, 0.0f) + fmaxf(sc, 0.0f);
    if (lab == 3) return fmaxf(0.09f + sc, 0.0f);
    return fmaxf(0.05f + sc, 0.0f) + fmaxf(-0.09f - sc, 0.0f); // labels 1|2
}

__device__ __forceinline__ float kval(float gm) {
    // K = exp(-M/REG), M = exp(-GM), REG = -0.2 -> exp(5*exp(-GM)); hw exp
    return __expf(5.0f * __expf(-gm));
}

__device__ __forceinline__ float dotw(const float f[16], float4 w0, float4 w1,
                                      float4 w2, float4 w3, float p) {
    p = fmaf(f[0], w0.x, p);  p = fmaf(f[1], w0.y, p);
    p = fmaf(f[2], w0.z, p);  p = fmaf(f[3], w0.w, p);
    p = fmaf(f[4], w1.x, p);  p = fmaf(f[5], w1.y, p);
    p = fmaf(f[6], w1.z, p);  p = fmaf(f[7], w1.w, p);
    p = fmaf(f[8], w2.x, p);  p = fmaf(f[9], w2.y, p);
    p = fmaf(f[10], w2.z, p); p = fmaf(f[11], w2.w, p);
    p = fmaf(f[12], w3.x, p); p = fmaf(f[13], w3.y, p);
    p = fmaf(f[14], w3.z, p); p = fmaf(f[15], w3.w, p);
    return p;
}

// select 4 consecutive floats starting at offset sh (0..3) from a|b; wave-uniform sh
#define SHIFT4(d, a, b, sh)                                                    \
    switch (sh) {                                                              \
    case 0: d[0] = a.x; d[1] = a.y; d[2] = a.z; d[3] = a.w; break;             \
    case 1: d[0] = a.y; d[1] = a.z; d[2] = a.w; d[3] = b.x; break;             \
    case 2: d[0] = a.z; d[1] = a.w; d[2] = b.x; d[3] = b.y; break;             \
    default: d[0] = a.w; d[1] = b.x; d[2] = b.y; d[3] = b.z; break;            \
    }

// ---- build kernels: register-shift alignment (no LDS, no barrier) ----

__global__ __launch_bounds__(256) void build_k1b(const float* __restrict__ dist,
                                                 const int* __restrict__ lab,
                                                 unsigned char* __restrict__ K,
                                                 unsigned char* __restrict__ gm) {
    int row = blockIdx.y;
    int j0 = blockIdx.x * BLKJ + threadIdx.x * 4;
    if (j0 >= KROW) return;
    size_t ib = (size_t)row * C1;
    int sh = row & 3;                      // C1 % 4 == 1 -> ib % 4 == row % 4
    long A = ((long)ib + j0 - sh) >> 2;    // aligned float4 index, coalesced per lane
    const long tot4 = ((long)R * C1) >> 2;
    const float4* g4 = reinterpret_cast<const float4*>(dist);
    const int4* l4 = reinterpret_cast<const int4*>(lab);
    float4 da = make_float4(0, 0, 0, 0), db = make_float4(0, 0, 0, 0);
    int4 la = make_int4(0, 0, 0, 0), lb = make_int4(0, 0, 0, 0);
    if (A < tot4) { da = g4[A]; la = l4[A]; }
    if (A + 1 < tot4) { db = g4[A + 1]; lb = l4[A + 1]; }
    float d[4]; int lv[4];
    SHIFT4(d, da, db, sh);
    SHIFT4(lv, la, lb, sh);
    float d0 = dist[ib];
    float val[4], gv[4];
#pragma unroll
    for (int k = 0; k < 4; ++k) {
        int j = j0 + k;
        val[k] = 0.0f; gv[k] = 0.0f;
        if (j < C1) {
            float g = gm_label(d[k] - d0, lv[k]);
            gv[k] = g;
            val[k] = kval(g);
        }
    }
    int p = 0;
    p = __builtin_amdgcn_cvt_pk_fp8_f32(val[0], val[1], p, false);
    p = __builtin_amdgcn_cvt_pk_fp8_f32(val[2], val[3], p, true);
    *reinterpret_cast<int*>(K + (size_t)row * KROW + j0) = p;
    if (gm) {
        int q = 0;
        q = __builtin_amdgcn_cvt_pk_fp8_f32(gv[0], gv[1], q, false);
        q = __builtin_amdgcn_cvt_pk_fp8_f32(gv[2], gv[3], q, true);
        *reinterpret_cast<int*>(gm + (size_t)row * KROW + j0) = q;
    }
}

__global__ __launch_bounds__(256) void diag_k(const float* __restrict__ dist,
                                              float* __restrict__ dcol) {
    int j = blockIdx.x * 256 + threadIdx.x;
    if (j < R) dcol[j] = dist[(size_t)j * C1 + 21 + j];
}

__global__ __launch_bounds__(256) void build_k2b(const float* __restrict__ dist,
                                                 const float* __restrict__ dcol,
                                                 unsigned char* __restrict__ K,
                                                 unsigned char* __restrict__ gm) {
    int row = blockIdx.y;
    int j0 = blockIdx.x * BLKJ + threadIdx.x * 4;
    if (j0 >= KROW) return;
    size_t ib = (size_t)row * C1 + 21;
    int sh = (int)(ib & 3);
    long A = ((long)ib + j0 - sh) >> 2;
    const long tot4 = ((long)R * C1) >> 2;
    const float4* g4 = reinterpret_cast<const float4*>(dist);
    float4 da = make_float4(0, 0, 0, 0), db = make_float4(0, 0, 0, 0);
    if (A < tot4) da = g4[A];
    if (A + 1 < tot4) db = g4[A + 1];
    float d[4];
    SHIFT4(d, da, db, sh);
    float4 dc = make_float4(0, 0, 0, 0);
    if (j0 < R) dc = *reinterpret_cast<const float4*>(dcol + j0);
    float dcv[4] = {dc.x, dc.y, dc.z, dc.w};
    float val[4], gv[4];
#pragma unroll
    for (int k = 0; k < 4; ++k) {
        int j = j0 + k;
        val[k] = 0.0f; gv[k] = 0.0f;
        if (j < C2) {
            float s = d[k] - dcv[k];
            float g = (j == row) ? 0.0f : fmaxf(0.09f + s, 0.0f);
            gv[k] = g;
            val[k] = kval(g);
        }
    }
    int p = 0;
    p = __builtin_amdgcn_cvt_pk_fp8_f32(val[0], val[1], p, false);
    p = __builtin_amdgcn_cvt_pk_fp8_f32(val[2], val[3], p, true);
    *reinterpret_cast<int*>(K + (size_t)row * KROW + j0) = p;
    if (gm) {
        int q = 0;
        q = __builtin_amdgcn_cvt_pk_fp8_f32(gv[0], gv[1], q, false);
        q = __builtin_amdgcn_cvt_pk_fp8_f32(gv[2], gv[3], q, true);
        *reinterpret_cast<int*>(gm + (size_t)row * KROW + j0) = q;
    }
}

// ---- byte transpose K[8192][KROW] -> KT[8224][TROW] via 64x64 LDS tile ----
__global__ __launch_bounds__(256) void transpose_k(const unsigned char* __restrict__ K,
                                                   unsigned char* __restrict__ KT) {
    __shared__ unsigned char tile[64][64];
    int i0 = blockIdx.x * 64;
    int j0 = blockIdx.y * 64;
    int t = threadIdx.x;
    int r = t >> 2, cb = (t & 3) << 4;
    if (j0 + cb < KROW) {
        int4 w = *reinterpret_cast<const int4*>(K + (size_t)(i0 + r) * KROW + j0 + cb);
        *reinterpret_cast<int4*>(&tile[r][cb]) = w;
    }
    __syncthreads();
    int jl = t >> 2, ib = (t & 3) << 4;
    if (j0 + jl < KROW) {
        unsigned char tmp[16];
#pragma unroll
        for (int k = 0; k < 16; ++k) tmp[k] = tile[ib + k][jl];
        *reinterpret_cast<int4*>(KT + (size_t)(j0 + jl) * TROW + i0 + ib) =
            *reinterpret_cast<const int4*>(tmp);
    }
}

// ---- shared pass bodies (plane-major LDS staging; `first` = uniform u = aval) ----

__device__ __forceinline__ void vpass_body(const unsigned char* __restrict__ KT,
                                           const float* __restrict__ u,
                                           float* __restrict__ v,
                                           int bb, int C, float bval,
                                           bool first, float aval,
                                           float4 (*wp)[516]) {
    int tx = threadIdx.x;
    if (!first) {
        const float4* g = reinterpret_cast<const float4*>(u);
#pragma unroll
        for (int k = 0; k < 8; ++k) {
            float4 a = g[tx + k * 256];
            wp[tx & 3][(tx >> 2) + k * 64] = a;
        }
        __syncthreads();
    }
    int lane = tx & 63, wv = tx >> 6;
    const int4* KTb = reinterpret_cast<const int4*>(KT);
    int ra = bb * 8 + wv * 2;
    const int4* K0 = KTb + (size_t)ra * NTC;
    const int4* K1 = K0 + NTC;
    float4 wa = make_float4(aval, aval, aval, aval);
    float p0 = 0.0f, p1 = 0.0f;
#pragma unroll
    for (int s = 0; s < 8; ++s) {
        int ch = s * 64 + lane;
        float4 w0, w1, w2, w3;
        if (first) { w0 = wa; w1 = wa; w2 = wa; w3 = wa; }
        else { w0 = wp[0][ch]; w1 = wp[1][ch]; w2 = wp[2][ch]; w3 = wp[3][ch]; }
        float f[16];
        fp8x16_to_f(K0[ch], f);
        p0 = dotw(f, w0, w1, w2, w3, p0);
        fp8x16_to_f(K1[ch], f);
        p1 = dotw(f, w0, w1, w2, w3, p1);
    }
#pragma unroll
    for (int off = 32; off; off >>= 1) {
        p0 += __shfl_down(p0, off, 64);
        p1 += __shfl_down(p1, off, 64);
    }
    if (lane == 0) {
        v[ra]     = (ra < C)     ? bval / p0 : 0.0f;
        v[ra + 1] = (ra + 1 < C) ? bval / p1 : 0.0f;
    }
}

__device__ __forceinline__ void upass_body(const unsigned char* __restrict__ K,
                                           const float* __restrict__ v,
                                           float* __restrict__ u,
                                           int bb, float aval,
                                           float4 (*wp)[516]) {
    int tx = threadIdx.x;
    {
        const float4* g = reinterpret_cast<const float4*>(v);
#pragma unroll
        for (int k = 0; k < 8; ++k) {
            float4 a = g[tx + k * 256];
            wp[tx & 3][(tx >> 2) + k * 64] = a;
        }
        if (tx < 8) {
            float4 a = g[2048 + tx];
            wp[tx & 3][(tx >> 2) + 512] = a;
        }
    }
    __syncthreads();
    int lane = tx & 63, wv = tx >> 6;
    const int4* Kb = reinterpret_cast<const int4*>(K);
    int ra = bb * 8 + wv * 2;
    const int4* K0 = Kb + (size_t)ra * NKC;
    const int4* K1 = K0 + NKC;
    float p0 = 0.0f, p1 = 0.0f;
#pragma unroll
    for (int s = 0; s < 8; ++s) {
        int ch = s * 64 + lane;
        float4 w0 = wp[0][ch], w1 = wp[1][ch], w2 = wp[2][ch], w3 = wp[3][ch];
        float f[16];
        fp8x16_to_f(K0[ch], f);
        p0 = dotw(f, w0, w1, w2, w3, p0);
        fp8x16_to_f(K1[ch], f);
        p1 = dotw(f, w0, w1, w2, w3, p1);
    }
    if (lane < 2) {
        int ch = 512 + lane;
        float4 w0 = wp[0][ch], w1 = wp[1][ch], w2 = wp[2][ch], w3 = wp[3][ch];
        float f[16];
        fp8x16_to_f(K0[ch], f);
        p0 = dotw(f, w0, w1, w2, w3, p0);
        fp8x16_to_f(K1[ch], f);
        p1 = dotw(f, w0, w1, w2, w3, p1);
    }
#pragma unroll
    for (int off = 32; off; off >>= 1) {
        p0 += __shfl_down(p0, off, 64);
        p1 += __shfl_down(p1, off, 64);
    }
    if (lane == 0) {
        u[ra]     = aval / p0;
        u[ra + 1] = aval / p1;
    }
}

// single-phase passes (sequential fallback)
__global__ __launch_bounds__(256) void v_pass(const unsigned char* __restrict__ KT,
                                              const float* __restrict__ u,
                                              float* __restrict__ v, int C, float bval,
                                              int first, float aval) {
    __shared__ float4 wp[4][516];
    vpass_body(KT, u, v, blockIdx.x, C, bval, first != 0, aval, wp);
}

__global__ __launch_bounds__(256) void u_pass(const unsigned char* __restrict__ K,
                                              const float* __restrict__ v,
                                              float* __restrict__ u, float aval) {
    __shared__ float4 wp[4][516];
    upass_body(K, v, u, blockIdx.x, aval, wp);
}

// dual-phase passes: first half of grid = phase 1, second half = phase 2
__global__ __launch_bounds__(256) void v_pass_dual(const unsigned char* __restrict__ KT1,
                                                   const unsigned char* __restrict__ KT2,
                                                   const float* __restrict__ u,   // u1 | u2
                                                   float* __restrict__ v,         // v1 | v2
                                                   float bval1, float bval2,
                                                   int first, float aval) {
    __shared__ float4 wp[4][516];
    int b = blockIdx.x;
    if (b < 1028)
        vpass_body(KT1, u, v, b, C1, bval1, first != 0, aval, wp);
    else
        vpass_body(KT2, u + R, v + CPF, b - 1028, C2, bval2, first != 0, aval, wp);
}

__global__ __launch_bounds__(256) void u_pass_dual(const unsigned char* __restrict__ K1,
                                                   const unsigned char* __restrict__ K2,
                                                   const float* __restrict__ v,
                                                   float* __restrict__ u, float aval) {
    __shared__ float4 wp[4][516];
    int b = blockIdx.x;
    if (b < 1024)
        upass_body(K1, v, u, b, aval, wp);
    else
        upass_body(K2, v + CPF, u + R, b - 1024, aval, wp);
}

// ---- loss reductions ----

__device__ __forceinline__ float2 block_reduce_2(float x, float y, float* sb) {
#pragma unroll
    for (int off = 32; off; off >>= 1) {
        x += __shfl_down(x, off, 64);
        y += __shfl_down(y, off, 64);
    }
    if ((threadIdx.x & 63) == 0) {
        int w = threadIdx.x >> 6;
        sb[w] = x; sb[4 + w] = y;
    }
    __syncthreads();
    float2 r;
    r.x = sb[0] + sb[1] + sb[2] + sb[3];
    r.y = sb[4] + sb[5] + sb[6] + sb[7];
    __syncthreads();
    return r;
}

__global__ __launch_bounds__(256) void loss1_gm(const unsigned char* __restrict__ K,
                                                const unsigned char* __restrict__ GM,
                                                const float* __restrict__ v,
                                                float* __restrict__ ratio) {
    __shared__ float sb[8];
    int i = blockIdx.x;
    const int4* Kr = reinterpret_cast<const int4*>(K + (size_t)i * KROW);
    const int4* Gr = reinterpret_cast<const int4*>(GM + (size_t)i * KROW);
    const float4* v4 = reinterpret_cast<const float4*>(v);
    float num = 0, den = 0;
    for (int c = threadIdx.x; c < NKC; c += 256) {
        float kf[16], gf[16];
        fp8x16_to_f(Kr[c], kf);
        fp8x16_to_f(Gr[c], gf);
#pragma unroll
        for (int q = 0; q < 4; ++q) {
            float4 w = v4[c * 4 + q];
            float k0 = kf[q * 4 + 0] * w.x, k1 = kf[q * 4 + 1] * w.y;
            float k2 = kf[q * 4 + 2] * w.z, k3 = kf[q * 4 + 3] * w.w;
            den += k0 + k1 + k2 + k3;
            num = fmaf(gf[q * 4 + 0], k0, num);
            num = fmaf(gf[q * 4 + 1], k1, num);
            num = fmaf(gf[q * 4 + 2], k2, num);
            num = fmaf(gf[q * 4 + 3], k3, num);
        }
    }
    float2 r = block_reduce_2(num, den, sb);
    if (threadIdx.x == 0) ratio[i] = r.x / r.y;
}

__global__ __launch_bounds__(256) void loss2_gm(const unsigned char* __restrict__ K,
                                                const unsigned char* __restrict__ GM,
                                                const float* __restrict__ v,
                                                float* __restrict__ ratio) {
    __shared__ float sb[8];
    int i = blockIdx.x;
    const int4* Kr = reinterpret_cast<const int4*>(K + (size_t)i * KROW);
    const int4* Gr = reinterpret_cast<const int4*>(GM + (size_t)i * KROW);
    const float4* v4 = reinterpret_cast<const float4*>(v);
    float num = 0, den = 0;
    for (int c = threadIdx.x; c < NKC; c += 256) {
        float kf[16], gf[16];
        fp8x16_to_f(Kr[c], kf);
        fp8x16_to_f(Gr[c], gf);
        int jb = c * 16;
#pragma unroll
        for (int q = 0; q < 4; ++q) {
            float4 w = v4[c * 4 + q];
            float m0 = (jb + q * 4 + 0 == i) ? 0.0f : 1.0f;
            float m1 = (jb + q * 4 + 1 == i) ? 0.0f : 1.0f;
            float m2 = (jb + q * 4 + 2 == i) ? 0.0f : 1.0f;
            float m3 = (jb + q * 4 + 3 == i) ? 0.0f : 1.0f;
            float k0 = kf[q * 4 + 0] * w.x * m0, k1 = kf[q * 4 + 1] * w.y * m1;
            float k2 = kf[q * 4 + 2] * w.z * m2, k3 = kf[q * 4 + 3] * w.w * m3;
            den += k0 + k1 + k2 + k3;
            num = fmaf(gf[q * 4 + 0], k0, num);
            num = fmaf(gf[q * 4 + 1], k1, num);
            num = fmaf(gf[q * 4 + 2], k2, num);
            num = fmaf(gf[q * 4 + 3], k3, num);
        }
    }
    float2 r = block_reduce_2(num, den, sb);
    if (threadIdx.x == 0) ratio[i] = r.x / r.y;
}

// fallback losses (read dist directly)
__global__ __launch_bounds__(256) void loss1_k(const unsigned char* __restrict__ K,
                                               const float* __restrict__ v,
                                               const float* __restrict__ dist,
                                               const int* __restrict__ lab,
                                               float* __restrict__ ratio) {
    __shared__ float sb[8];
    int i = blockIdx.x;
    size_t ib = (size_t)i * C1;
    float d0 = dist[ib];
    const unsigned char* Kr = K + (size_t)i * KROW;
    float num = 0, den = 0;
    for (int j0 = threadIdx.x * 4; j0 < C1; j0 += 1024) {
        int p = *reinterpret_cast<const int*>(Kr + j0);
#pragma unroll
        for (int k = 0; k < 4; ++k) {
            int j = j0 + k;
            int jc = (j < C1) ? j : (C1 - 1);
            float kv = fp8_to_f(p >> (k * 8)) * v[jc];
            float g = gm_label(dist[ib + jc] - d0, lab[ib + jc]);
            den += kv;
            num = fmaf(g, kv, num);
        }
    }
    float2 r = block_reduce_2(num, den, sb);
    if (threadIdx.x == 0) ratio[i] = r.x / r.y;
}

__global__ __launch_bounds__(256) void loss2_k(const unsigned char* __restrict__ K,
                                               const float* __restrict__ v,
                                               const float* __restrict__ dist,
                                               const float* __restrict__ dcol,
                                               float* __restrict__ ratio) {
    __shared__ float sb[8];
    int i = blockIdx.x;
    const unsigned char* Kr = K + (size_t)i * KROW;
    const float* Dr = dist + (size_t)i * C1 + 21;
    float num = 0, den = 0;
    for (int j0 = threadIdx.x * 4; j0 < C2; j0 += 1024) {
        int p = *reinterpret_cast<const int*>(Kr + j0);
#pragma unroll
        for (int k = 0; k < 4; ++k) {
            int j = j0 + k;
            if (j == i) continue;
            float kv = fp8_to_f(p >> (k * 8)) * v[j];
            float h = fmaxf(0.09f + Dr[j] - dcol[j], 0.0f);
            den += kv;
            num = fmaf(h, kv, num);
        }
    }
    float2 r = block_reduce_2(num, den, sb);
    if (threadIdx.x == 0) ratio[i] = r.x / r.y;
}

__global__ __launch_bounds__(256) void final_k(const float* __restrict__ r1,
                                               const float* __restrict__ r2,
                                               float* __restrict__ out) {
    __shared__ float sb[8];
    float s1 = 0, s2 = 0;
    for (int i = threadIdx.x; i < R; i += 256) { s1 += r1[i]; s2 += r2[i]; }
    float2 t = block_reduce_2(s1, s2, sb);
    if (threadIdx.x == 0)
        out[0] = t.x / ((float)R * (float)C1) + t.y / ((float)R * (float)C2);
}

static void run_phase_seq(const unsigned char* K, const unsigned char* KT,
                          float* u, float* v, int C, hipStream_t stream) {
    float aval = 1.0f / (float)R;
    float bval = 1.0f / (float)C;
    for (int t = 0; t < 50; ++t) {
        v_pass<<<dim3(CPF / 8), 256, 0, stream>>>(KT, u, v, C, bval, t == 0, aval);
        if (t < 49)
            u_pass<<<dim3(R / 8), 256, 0, stream>>>(K, v, u, aval);
    }
}

extern "C" void kernel_launch(void* const* d_in, const int* in_sizes, int n_in,
                              void* d_out, int out_size, void* d_ws, size_t ws_size,
                              hipStream_t stream) {
    const float* dist = (const float*)d_in[0];
    const int* lab = (const int*)d_in[1];
    float* out = (float*)d_out;
    char* ws = (char*)d_ws;

    const size_t kb = (size_t)R * KROW;       // 67,371,008 (== KROW*TROW)
    const size_t small_dual = (2 * (size_t)CPF + 2 * R + 3 * R) * sizeof(float);
    const size_t small_seq = ((size_t)CPF + 4 * R) * sizeof(float);
    const size_t need_dual = 6 * kb + small_dual;     // ~404 MB
    const size_t need_gm_seq = 3 * kb + small_seq;    // ~202 MB
    const size_t need_base = 2 * kb + small_seq;      // ~135 MB
    if (ws_size < need_base) return;

    const float aval = 1.0f / (float)R;
    const int gbx = (KROW + BLKJ - 1) / BLKJ;         // 9
    const dim3 gT(R / 64, (KROW + 63) / 64);

    if (ws_size >= need_dual) {
        // ---- dual-phase path ----
        size_t off = 0;
        unsigned char* K1 = (unsigned char*)(ws + off);  off += kb;
        unsigned char* K2 = (unsigned char*)(ws + off);  off += kb;
        unsigned char* K1T = (unsigned char*)(ws + off); off += kb;
        unsigned char* K2T = (unsigned char*)(ws + off); off += kb;
        unsigned char* GM1 = (unsigned char*)(ws + off); off += kb;
        unsigned char* GM2 = (unsigned char*)(ws + off); off += kb;
        float* v = (float*)(ws + off);    off += 2 * (size_t)CPF * sizeof(float);
        float* u = (float*)(ws + off);    off += 2 * (size_t)R * sizeof(float);
        float* dcol = (float*)(ws + off); off += (size_t)R * sizeof(float);
        float* rat1 = (float*)(ws + off); off += (size_t)R * sizeof(float);
        float* rat2 = (float*)(ws + off); off += (size_t)R * sizeof(float);

        diag_k<<<dim3(R / 256), 256, 0, stream>>>(dist, dcol);
        build_k1b<<<dim3(gbx, R), 256, 0, stream>>>(dist, lab, K1, GM1);
        build_k2b<<<dim3(gbx, R), 256, 0, stream>>>(dist, dcol, K2, GM2);
        transpose_k<<<gT, 256, 0, stream>>>(K1, K1T);
        transpose_k<<<gT, 256, 0, stream>>>(K2, K2T);
        for (int t = 0; t < 50; ++t) {
            v_pass_dual<<<dim3(2 * (CPF / 8)), 256, 0, stream>>>(
                K1T, K2T, u, v, 1.0f / (float)C1, 1.0f / (float)C2, t == 0, aval);
            if (t < 49)
                u_pass_dual<<<dim3(2 * (R / 8)), 256, 0, stream>>>(K1, K2, v, u, aval);
        }
        loss1_gm<<<dim3(R), 256, 0, stream>>>(K1, GM1, v, rat1);
        loss2_gm<<<dim3(R), 256, 0, stream>>>(K2, GM2, v + CPF, rat2);
        final_k<<<dim3(1), 256, 0, stream>>>(rat1, rat2, out);
        return;
    }

    // ---- sequential path (aligned builds, no GM-dual) ----
    bool useGM = ws_size >= need_gm_seq;
    size_t off = 0;
    unsigned char* K = (unsigned char*)(ws + off);  off += kb;
    unsigned char* KT = (unsigned char*)(ws + off); off += kb;
    unsigned char* GM = nullptr;
    if (useGM) { GM = (unsigned char*)(ws + off); off += kb; }
    float* v = (float*)(ws + off);    off += (size_t)CPF * sizeof(float);
    float* u = (float*)(ws + off);    off += (size_t)R * sizeof(float);
    float* dcol = (float*)(ws + off); off += (size_t)R * sizeof(float);
    float* rat1 = (float*)(ws + off); off += (size_t)R * sizeof(float);
    float* rat2 = (float*)(ws + off); off += (size_t)R * sizeof(float);

    build_k1b<<<dim3(gbx, R), 256, 0, stream>>>(dist, lab, K, GM);
    transpose_k<<<gT, 256, 0, stream>>>(K, KT);
    run_phase_seq(K, KT, u, v, C1, stream);
    if (useGM)
        loss1_gm<<<dim3(R), 256, 0, stream>>>(K, GM, v, rat1);
    else
        loss1_k<<<dim3(R), 256, 0, stream>>>(K, v, dist, lab, rat1);

    diag_k<<<dim3(R / 256), 256, 0, stream>>>(dist, dcol);
    build_k2b<<<dim3(gbx, R), 256, 0, stream>>>(dist, dcol, K, GM);
    transpose_k<<<gT, 256, 0, stream>>>(K, KT);
    run_phase_seq(K, KT, u, v, C2, stream);
    if (useGM)
        loss2_gm<<<dim3(R), 256, 0, stream>>>(K, GM, v, rat2);
    else
        loss2_k<<<dim3(R), 256, 0, stream>>>(K, v, dist, dcol, rat2);

    final_k<<<dim3(1), 256, 0, stream>>>(rat1, rat2, out);
}